// Round 6
// baseline (1332.729 us; speedup 1.0000x reference)
//
#include <hip/hip_runtime.h>

// B=128, S=196, K=512, T=15, V=32000, E=H=512
typedef _Float16 half_t;
typedef float    floatx4 __attribute__((ext_vector_type(4)));
typedef _Float16 halfx8  __attribute__((ext_vector_type(8)));
typedef _Float16 halfx2  __attribute__((ext_vector_type(2)));

__device__ __forceinline__ float tanh_f(float x) {
  float e = __expf(2.0f * x);
  return 1.0f - 2.0f / (e + 1.0f);
}
__device__ __forceinline__ float sigmoid_f(float x) {
  return 1.0f / (1.0f + __expf(-x));
}

// async global -> LDS, 16B per lane (dest = wave-uniform base + lane*16)
__device__ __forceinline__ void gl16(const void* g, void* s) {
  __builtin_amdgcn_global_load_lds((__attribute__((address_space(1))) unsigned int*)g,
                                   (__attribute__((address_space(3))) unsigned int*)s,
                                   16, 0, 0);
}

// bijective XCD swizzle (m204)
__device__ __forceinline__ int xcd_swz(int bid, int nwg) {
  int q = nwg >> 3, r = nwg & 7, x = bid & 7, p = bid >> 3;
  return (x < r ? x * (q + 1) : r * (q + 1) + (x - r) * q) + p;
}

// device-scope grid barrier (28 co-resident blocks)
__device__ __forceinline__ void gbar(int* cnt, int* gen, int nb) {
  __syncthreads();
  if (threadIdx.x == 0) {
    int g = __hip_atomic_load(gen, __ATOMIC_RELAXED, __HIP_MEMORY_SCOPE_AGENT);
    if (__hip_atomic_fetch_add(cnt, 1, __ATOMIC_ACQ_REL, __HIP_MEMORY_SCOPE_AGENT) == nb - 1) {
      __hip_atomic_store(cnt, 0, __ATOMIC_RELAXED, __HIP_MEMORY_SCOPE_AGENT);
      __hip_atomic_store(gen, g + 1, __ATOMIC_RELEASE, __HIP_MEMORY_SCOPE_AGENT);
    } else {
      while (__hip_atomic_load(gen, __ATOMIC_ACQUIRE, __HIP_MEMORY_SCOPE_AGENT) == g) {
        __builtin_amdgcn_s_sleep(8);
      }
    }
  }
  __syncthreads();
}

// ---------------- fused precompute: all elementwise prep in ONE launch ----------------
__device__ __forceinline__ void cvt4(const float* __restrict__ src,
                                     half_t* __restrict__ dst, int blk) {
  int i = (blk * 256 + threadIdx.x) * 4;
  float4 v = *(const float4*)(src + i);
  halfx2 a; a[0] = (half_t)v.x; a[1] = (half_t)v.y;
  halfx2 b; b[0] = (half_t)v.z; b[1] = (half_t)v.w;
  *(halfx2*)(dst + i) = a;
  *(halfx2*)(dst + i + 2) = b;
}

__global__ __launch_bounds__(256) void k_prep(const float* __restrict__ fc2_w, half_t* __restrict__ fc2w_h,
                                              const float* __restrict__ features, half_t* __restrict__ featf,
                                              const float* __restrict__ fc1_w, half_t* __restrict__ fc1w_h,
                                              const float* __restrict__ att_wk, const float* __restrict__ fc0_w,
                                              half_t* __restrict__ wkfc0,
                                              const float* __restrict__ gru_whh, const float* __restrict__ att_wq,
                                              half_t* __restrict__ bcat2,
                                              const float* __restrict__ gru_wih, half_t* __restrict__ wihx,
                                              half_t* __restrict__ wihc,
                                              const float* __restrict__ emb, const int* __restrict__ cap,
                                              half_t* __restrict__ embg,
                                              const float* __restrict__ fc0_b, float* __restrict__ biasc,
                                              float4* __restrict__ zbase) {
  const int bb = blockIdx.x, tid = threadIdx.x;
  if (bb < 16000) {                       // fc2_w cvt (32000x512)
    cvt4(fc2_w, fc2w_h, bb);
  } else if (bb < 28544) {                // features cvt (25088x512)
    cvt4(features, featf, bb - 16000);
  } else if (bb < 28800) {                // fc1_w cvt
    cvt4(fc1_w, fc1w_h, bb - 28544);
  } else if (bb < 29056) {                // att_wk -> wkfc0[0:512]
    cvt4(att_wk, wkfc0, bb - 28800);
  } else if (bb < 29312) {                // fc0_w -> wkfc0[512:1024]
    cvt4(fc0_w, wkfc0 + (size_t)512 * 512, bb - 29056);
  } else if (bb < 30080) {                // whh -> bcat2[0:1536]
    cvt4(gru_whh, bcat2, bb - 29312);
  } else if (bb < 30336) {                // wq -> bcat2[1536:2048]
    cvt4(att_wq, bcat2 + (size_t)1536 * 512, bb - 30080);
  } else if (bb < 31872) {                // wih split (1536 rows)
    int row = bb - 30336, j = tid * 2;
    float2 a = *(const float2*)(gru_wih + (size_t)row * 1024 + j);
    float2 b = *(const float2*)(gru_wih + (size_t)row * 1024 + 512 + j);
    halfx2 ax; ax[0] = (half_t)a.x; ax[1] = (half_t)a.y;
    halfx2 bx; bx[0] = (half_t)b.x; bx[1] = (half_t)b.y;
    *(halfx2*)(wihx + (size_t)row * 512 + j) = ax;
    *(halfx2*)(wihc + (size_t)row * 512 + j) = bx;
  } else if (bb < 33792) {                // embedding gather (1920 rows)
    int row = bb - 31872;
    int b = row / 15, t = row - b * 15;
    int c = cap[b * 16 + t];
    const float* s = emb + (size_t)c * 512;
    int e = tid * 2;
    float2 v = *(const float2*)(s + e);
    halfx2 o; o[0] = (half_t)v.x; o[1] = (half_t)v.y;
    *(halfx2*)(embg + (size_t)row * 512 + e) = o;
  } else if (bb < 33796) {                // biasc (1024 floats)
    int i = (bb - 33792) * 256 + tid;
    biasc[i] = (i < 512) ? 0.f : fc0_b[i - 512];
  } else {                                // zero ghq+hbuf+bar (321 blocks)
    zbase[(size_t)(bb - 33796) * 256 + tid] = make_float4(0.f, 0.f, 0.f, 0.f);
  }
}

// ---------------- LDS-staged MFMA GEMM (m97 structure), f16 A and B ----------------
// C[m][n] = sum_k A[m][k]*B[n][k] (+bias[n]); tile 128x128, BK=32, 4 waves.
template <bool OUT_F16>
__device__ __forceinline__ void gemm128_body(const half_t* __restrict__ Ap,
                                             const half_t* __restrict__ Bp,
                                             const float* __restrict__ bias,
                                             void* __restrict__ Cp,
                                             const int Kd, const int ldc,
                                             const int m0, const int n0,
                                             char* smem) {
  constexpr int ABYTES = 128 * 32 * 2;
  constexpr int BBYTES = 128 * 32 * 2;

  const int l = threadIdx.x & 63;
  const int w = threadIdx.x >> 6;

  const half_t* gA = Ap + (size_t)(m0 + w * 32 + (l >> 2)) * Kd + (l & 3) * 8;
  const half_t* gB = Bp + (size_t)(n0 + w * 32 + (l >> 2)) * Kd + (l & 3) * 8;

  const int fr = l & 15;
  const int kq = (l >> 4) * 8;
  const int mh = (w & 1) * 64;
  const int nh = (w >> 1) * 64;

  floatx4 acc[4][4];
#pragma unroll
  for (int i = 0; i < 4; ++i)
#pragma unroll
    for (int j = 0; j < 4; ++j) { floatx4 z = {0.f, 0.f, 0.f, 0.f}; acc[i][j] = z; }

  const int NT = Kd >> 5;

  auto stage = [&](int tt) {
    const int k0 = tt * 32;
    char* aD = smem + (tt & 1) * ABYTES;
    char* bD = smem + 2 * ABYTES + (tt & 1) * BBYTES;
    const half_t* g = gA + k0;
    gl16(g, aD + (w * 32) * 64);
    gl16(g + (size_t)16 * Kd, aD + (w * 32 + 16) * 64);
    const half_t* g2 = gB + k0;
    gl16(g2, bD + (w * 32) * 64);
    gl16(g2 + (size_t)16 * Kd, bD + (w * 32 + 16) * 64);
  };

  stage(0);

  for (int t = 0; t < NT; ++t) {
    __syncthreads();                 // drains stage(t)
    if (t + 1 < NT) stage(t + 1);    // prefetch into other buffer
    const char* aB = smem + (t & 1) * ABYTES;
    const char* bB = smem + 2 * ABYTES + (t & 1) * BBYTES;
    halfx8 af[4], bf[4];
#pragma unroll
    for (int i = 0; i < 4; ++i) {
      af[i] = *(const halfx8*)((const half_t*)aB + (size_t)(mh + i * 16 + fr) * 32 + kq);
      bf[i] = *(const halfx8*)((const half_t*)bB + (size_t)(nh + i * 16 + fr) * 32 + kq);
    }
#pragma unroll
    for (int i = 0; i < 4; ++i)
#pragma unroll
      for (int j = 0; j < 4; ++j)
        acc[i][j] = __builtin_amdgcn_mfma_f32_16x16x32_f16(af[i], bf[j], acc[i][j], 0, 0, 0);
  }

#pragma unroll
  for (int j = 0; j < 4; ++j) {
    const int n = n0 + nh + j * 16 + fr;
    const float bv = bias ? bias[n] : 0.0f;
#pragma unroll
    for (int i = 0; i < 4; ++i) {
      const int mb = m0 + mh + i * 16 + (l >> 4) * 4;
#pragma unroll
      for (int r = 0; r < 4; ++r) {
        const float v = acc[i][j][r] + bv;
        const size_t ci = (size_t)(mb + r) * ldc + n;
        if constexpr (OUT_F16) ((half_t*)Cp)[ci] = (half_t)v;
        else                   ((float*)Cp)[ci] = v;
      }
    }
  }
}

// generic wrapper: grid.x = n-tiles (fast), grid.y = m-tiles
template <bool OUT_F16>
__global__ __launch_bounds__(256) void k_gemm_lds(const half_t* __restrict__ Ap,
                                                  const half_t* __restrict__ Bp,
                                                  const float* __restrict__ bias,
                                                  void* __restrict__ Cp,
                                                  int Kd, int ldc) {
  __shared__ __align__(16) char smem[32768];
  gemm128_body<OUT_F16>(Ap, Bp, bias, Cp, Kd, ldc,
                        blockIdx.y * 128, blockIdx.x * 128, smem);
}

// kpfp GEMM: 1568 blocks, XCD-chunked (1568%8==0), works n-fast (8 n-tiles share A panel)
__global__ __launch_bounds__(256) void k_kpfp(const half_t* __restrict__ featf,
                                              const half_t* __restrict__ wkfc0,
                                              const float* __restrict__ biasc,
                                              half_t* __restrict__ kpfp) {
  __shared__ __align__(16) char smem[32768];
  const int w = (blockIdx.x & 7) * 196 + (blockIdx.x >> 3);
  const int n0 = (w & 7) * 128;
  const int m0 = (w >> 3) * 128;
  gemm128_body<true>(featf, wkfc0, biasc, kpfp, 512, 1024, m0, n0, smem);
}

// final fc2 GEMM over all timesteps: C[1920][32000] = hall @ fc2w^T + fc2_b
__global__ __launch_bounds__(256) void k_fc2_final(const half_t* __restrict__ hall,
                                                   const half_t* __restrict__ fc2w,
                                                   const float* __restrict__ fc2b,
                                                   float* __restrict__ outp) {
  __shared__ __align__(16) char smem[32768];
  const int w = xcd_swz(blockIdx.x, 3750);
  const int m0 = (w % 15) * 128;
  const int n0 = (w / 15) * 128;
  gemm128_body<false>(hall, fc2w, fc2b, outp, 512, 32000, m0, n0, smem);
}

// ---------------- scores: one wave per (b,s): tanh(q_b + kp_bs) . attv ----------------
__global__ __launch_bounds__(256) void k_scores(const half_t* __restrict__ kpfp,
                                                const float* __restrict__ ghq,
                                                const float* __restrict__ attv,
                                                float* __restrict__ scores) {
  int w = blockIdx.x * 4 + (threadIdx.x >> 6);   // 0..25087 == b*196+s
  int l = threadIdx.x & 63;
  int b = w / 196;
  halfx8 kv = *(const halfx8*)(kpfp + (size_t)w * 1024 + l * 8);
  const float* qr = ghq + (size_t)b * 2048 + 1536 + l * 8;
  float4 q0 = *(const float4*)qr;
  float4 q1 = *(const float4*)(qr + 4);
  float4 a0 = *(const float4*)(attv + l * 8);
  float4 a1 = *(const float4*)(attv + l * 8 + 4);
  float acc = a0.x * tanh_f(q0.x + (float)kv[0]);
  acc += a0.y * tanh_f(q0.y + (float)kv[1]);
  acc += a0.z * tanh_f(q0.z + (float)kv[2]);
  acc += a0.w * tanh_f(q0.w + (float)kv[3]);
  acc += a1.x * tanh_f(q1.x + (float)kv[4]);
  acc += a1.y * tanh_f(q1.y + (float)kv[5]);
  acc += a1.z * tanh_f(q1.z + (float)kv[6]);
  acc += a1.w * tanh_f(q1.w + (float)kv[7]);
#pragma unroll
  for (int off = 32; off > 0; off >>= 1) acc += __shfl_xor(acc, off, 64);
  if (l == 0) scores[w] = acc;
}

// ---------------- softmax + ctx = w @ featp (f16 out) ----------------
__global__ __launch_bounds__(256) void k_ctx(const float* __restrict__ scores,
                                             const half_t* __restrict__ kpfp,
                                             half_t* __restrict__ ctxo) {
  const int b = blockIdx.x, kt = blockIdx.y * 128, t = threadIdx.x;
  __shared__ float sw[196], red[256];
  float sc = (t < 196) ? scores[b * 196 + t] : -1e30f;
  red[t] = sc; __syncthreads();
  for (int o = 128; o > 0; o >>= 1) { if (t < o) red[t] = fmaxf(red[t], red[t + o]); __syncthreads(); }
  float mx = red[0]; __syncthreads();
  float e = (t < 196) ? __expf(sc - mx) : 0.f;
  red[t] = e; __syncthreads();
  for (int o = 128; o > 0; o >>= 1) { if (t < o) red[t] += red[t + o]; __syncthreads(); }
  float inv = 1.0f / red[0];
  if (t < 196) sw[t] = e * inv;
  __syncthreads();
  const int kk = t & 127, half = t >> 7, s0 = half * 98;
  const half_t* fp = kpfp + (size_t)(b * 196 + s0) * 1024 + 512 + kt + kk;
  float acc = 0.f;
#pragma unroll 7
  for (int i = 0; i < 98; ++i) acc += sw[s0 + i] * (float)fp[(size_t)i * 1024];
  red[t] = acc; __syncthreads();
  if (t < 128) ctxo[(size_t)b * 512 + kt + t] = (half_t)(red[t] + red[t + 128]);
}

// ---------------- fused GRU tail: gic GEMM -> gates -> ghq GEMM, one launch ----------
// 28 blocks x 256 threads, 2 device-scope barriers.
__global__ __launch_bounds__(256, 1) void k_cell(const half_t* __restrict__ ctxo,
                                                 const half_t* __restrict__ wihc,
                                                 float* __restrict__ gic,
                                                 const float* __restrict__ gix,
                                                 const float* __restrict__ bih,
                                                 const float* __restrict__ bhh,
                                                 float* __restrict__ ghq,
                                                 float* __restrict__ hbuf,
                                                 half_t* __restrict__ h_h,
                                                 half_t* __restrict__ hall,
                                                 const half_t* __restrict__ bcat2,
                                                 int* __restrict__ bar, int step) {
  __shared__ __align__(16) char smem[32768];
  const int blk = blockIdx.x, tid = threadIdx.x;
  const int nb = gridDim.x;

  // phase 1: gic = ctxo @ wihc^T  (128 x 1536), blocks 0..11
  if (blk < 12)
    gemm128_body<false>(ctxo, wihc, nullptr, gic, 512, 1536, 0, blk * 128, smem);
  gbar(bar, bar + 1, nb);

  // phase 2: gates, grid-stride over 32768 float2 items
  for (int it = blk * 256 + tid; it < 32768; it += nb * 256) {
    const int b = it >> 8, n = (it & 255) * 2;
    const float* gx = gix + (size_t)(b * 15 + step) * 1536;
    const float* gc = gic + (size_t)b * 1536;
    const float* gh = ghq + (size_t)b * 2048;
    float2 hv = *(float2*)(hbuf + (size_t)b * 512 + n);
    float2 res;
#pragma unroll
    for (int u = 0; u < 2; ++u) {
      const int nn = n + u;
      float ir  = gx[nn]        + gc[nn]        + bih[nn];
      float iz  = gx[nn + 512]  + gc[nn + 512]  + bih[nn + 512];
      float in_ = gx[nn + 1024] + gc[nn + 1024] + bih[nn + 1024];
      float hr  = gh[nn]        + bhh[nn];
      float hz  = gh[nn + 512]  + bhh[nn + 512];
      float hn  = gh[nn + 1024] + bhh[nn + 1024];
      float r = sigmoid_f(ir + hr);
      float z = sigmoid_f(iz + hz);
      float g2 = tanh_f(in_ + r * hn);
      float hnew = (1.0f - z) * g2 + z * (u ? hv.y : hv.x);
      if (u) res.y = hnew; else res.x = hnew;
    }
    *(float2*)(hbuf + (size_t)b * 512 + n) = res;
    halfx2 h2; h2[0] = (half_t)res.x; h2[1] = (half_t)res.y;
    *(halfx2*)(h_h + (size_t)b * 512 + n) = h2;
    *(halfx2*)(hall + (size_t)(b * 15 + step) * 512 + n) = h2;
  }
  gbar(bar, bar + 1, nb);

  // phase 3: ghq = h @ [whh|wq]^T  (128 x 2048), blocks 0..15
  if (blk < 16)
    gemm128_body<false>(h_h, bcat2, nullptr, ghq, 512, 2048, 0, blk * 128, smem);
}

extern "C" void kernel_launch(void* const* d_in, const int* in_sizes, int n_in,
                              void* d_out, int out_size, void* d_ws, size_t ws_size,
                              hipStream_t stream) {
  (void)in_sizes; (void)n_in; (void)out_size; (void)ws_size;
  const float* features = (const float*)d_in[0];
  const int*   captions = (const int*)d_in[1];
  const float* emb      = (const float*)d_in[2];
  const float* fc1_w    = (const float*)d_in[3];
  const float* fc1_b    = (const float*)d_in[4];
  const float* att_wq   = (const float*)d_in[5];
  const float* att_wk   = (const float*)d_in[6];
  const float* att_v    = (const float*)d_in[7];
  const float* fc0_w    = (const float*)d_in[8];
  const float* fc0_b    = (const float*)d_in[9];
  const float* gru_wih  = (const float*)d_in[10];
  const float* gru_whh  = (const float*)d_in[11];
  const float* gru_bih  = (const float*)d_in[12];
  const float* gru_bhh  = (const float*)d_in[13];
  const float* fc2_w    = (const float*)d_in[14];
  const float* fc2_b    = (const float*)d_in[15];
  float* out = (float*)d_out;

  // workspace layout (~137 MB)
  char* p = (char*)d_ws;
  half_t* kpfp   = (half_t*)p; p += (size_t)25088 * 1024 * 2; // [:,0:512]=kp, [:,512:1024]=featp+fc0_b
  half_t* fc2w_h = (half_t*)p; p += (size_t)32000 * 512 * 2;
  float*  gix    = (float*)p;  p += (size_t)1920 * 1536 * 4;  // x-path GRU gates, all t
  half_t* wihx_h = (half_t*)p; p += (size_t)1536 * 512 * 2;
  half_t* wihc_h = (half_t*)p; p += (size_t)1536 * 512 * 2;
  half_t* bcat2  = (half_t*)p; p += (size_t)2048 * 512 * 2;   // rows 0:1536=whh, 1536:2048=wq
  half_t* wkfc0  = (half_t*)p; p += (size_t)1024 * 512 * 2;   // rows 0:512=att_wk, 512:1024=fc0_w
  half_t* fc1w_h = (half_t*)p; p += (size_t)512 * 512 * 2;
  half_t* embg_h = (half_t*)p; p += (size_t)1920 * 512 * 2;
  half_t* xproj_h= (half_t*)p; p += (size_t)1920 * 512 * 2;
  float*  biasc  = (float*)p;  p += (size_t)1024 * 4;
  float*  ghq    = (float*)p;  p += (size_t)128 * 2048 * 4;   // cols 0:1536=gh, 1536:2048=q  (zeroed)
  float*  hbuf   = (float*)p;  p += (size_t)128 * 512 * 4;    // zeroed
  int*    bar    = (int*)p;    p += 16;                       // barrier state (zeroed)
  float*  scores = (float*)p;  p += (size_t)128 * 196 * 4;
  float*  gic    = (float*)p;  p += (size_t)128 * 1536 * 4;
  half_t* ctxo   = (half_t*)p; p += (size_t)128 * 512 * 2;
  half_t* h_h    = (half_t*)p; p += (size_t)128 * 512 * 2;
  half_t* featf  = (half_t*)p; p += (size_t)25088 * 512 * 2;  // features, f16
  half_t* hall   = (half_t*)p; p += (size_t)1920 * 512 * 2;   // all h_t, rows b*15+t

  // ---- precompute: ONE fused elementwise launch ----
  // zero range: ghq (1 MB) + hbuf (256 KB) + bar; 321 blocks x 4 KB (slop into scores ok)
  k_prep<<<dim3(34117), 256, 0, stream>>>(fc2_w, fc2w_h, features, featf,
                                          fc1_w, fc1w_h, att_wk, fc0_w, wkfc0,
                                          gru_whh, att_wq, bcat2,
                                          gru_wih, wihx_h, wihc_h,
                                          emb, captions, embg_h,
                                          fc0_b, biasc, (float4*)ghq);
  // xproj = embg @ fc1_w^T + fc1_b  (1920 x 512, f16 out)
  k_gemm_lds<true><<<dim3(4, 15), 256, 0, stream>>>(embg_h, fc1w_h, fc1_b, xproj_h, 512, 512);
  // kpfp = featf @ [wk|fc0]^T + [0|fc0_b]  (25088 x 1024, f16 out), XCD-chunked
  k_kpfp<<<dim3(1568), 256, 0, stream>>>(featf, wkfc0, biasc, kpfp);
  // gix = xproj @ wihx^T  (1920 x 1536, f32 out)
  k_gemm_lds<false><<<dim3(12, 15), 256, 0, stream>>>(xproj_h, wihx_h, nullptr, gix, 512, 1536);

  // ---- decode loop: 3 launches/step ----
  for (int t = 0; t < 15; ++t) {
    k_scores<<<dim3(6272), 256, 0, stream>>>(kpfp, ghq, att_v, scores);
    k_ctx<<<dim3(128, 4), 256, 0, stream>>>(scores, kpfp, ctxo);
    k_cell<<<dim3(28), 256, 0, stream>>>(ctxo, wihc_h, gic, gix, gru_bih, gru_bhh,
                                         ghq, hbuf, h_h, hall, bcat2, bar, t);
  }
  // out[b,t,:] = hall[b*15+t] @ fc2^T + fc2_b  (1920 x 32000), one big GEMM
  k_fc2_final<<<dim3(3750), 256, 0, stream>>>(hall, fc2w_h, fc2_b, out);
}

// Round 7
// 1200.534 us; speedup vs baseline: 1.1101x; 1.1101x over previous
//
#include <hip/hip_runtime.h>

// B=128, S=196, K=512, T=15, V=32000, E=H=512
typedef _Float16 half_t;
typedef float    floatx4 __attribute__((ext_vector_type(4)));
typedef _Float16 halfx8  __attribute__((ext_vector_type(8)));
typedef _Float16 halfx2  __attribute__((ext_vector_type(2)));

__device__ __forceinline__ float tanh_f(float x) {
  float e = __expf(2.0f * x);
  return 1.0f - 2.0f / (e + 1.0f);
}
__device__ __forceinline__ float sigmoid_f(float x) {
  return 1.0f / (1.0f + __expf(-x));
}

// async global -> LDS, 16B per lane (dest = wave-uniform base + lane*16)
__device__ __forceinline__ void gl16(const void* g, void* s) {
  __builtin_amdgcn_global_load_lds((__attribute__((address_space(1))) unsigned int*)g,
                                   (__attribute__((address_space(3))) unsigned int*)s,
                                   16, 0, 0);
}

// bijective XCD swizzle (m204)
__device__ __forceinline__ int xcd_swz(int bid, int nwg) {
  int q = nwg >> 3, r = nwg & 7, x = bid & 7, p = bid >> 3;
  return (x < r ? x * (q + 1) : r * (q + 1) + (x - r) * q) + p;
}

// ---------------- fused precompute: all elementwise prep in ONE launch ----------------
__device__ __forceinline__ void cvt4(const float* __restrict__ src,
                                     half_t* __restrict__ dst, int blk) {
  int i = (blk * 256 + threadIdx.x) * 4;
  float4 v = *(const float4*)(src + i);
  halfx2 a; a[0] = (half_t)v.x; a[1] = (half_t)v.y;
  halfx2 b; b[0] = (half_t)v.z; b[1] = (half_t)v.w;
  *(halfx2*)(dst + i) = a;
  *(halfx2*)(dst + i + 2) = b;
}

__global__ __launch_bounds__(256) void k_prep(const float* __restrict__ fc2_w, half_t* __restrict__ fc2w_h,
                                              const float* __restrict__ features, half_t* __restrict__ featf,
                                              const float* __restrict__ fc1_w, half_t* __restrict__ fc1w_h,
                                              const float* __restrict__ att_wk, const float* __restrict__ fc0_w,
                                              half_t* __restrict__ wkfc0,
                                              const float* __restrict__ gru_whh, const float* __restrict__ att_wq,
                                              half_t* __restrict__ bcat2,
                                              const float* __restrict__ gru_wih, half_t* __restrict__ wihx,
                                              half_t* __restrict__ wihc,
                                              const float* __restrict__ emb, const int* __restrict__ cap,
                                              half_t* __restrict__ embg,
                                              const float* __restrict__ fc0_b, float* __restrict__ biasc,
                                              float4* __restrict__ zbase) {
  const int bb = blockIdx.x, tid = threadIdx.x;
  if (bb < 16000) {                       // fc2_w cvt (32000x512)
    cvt4(fc2_w, fc2w_h, bb);
  } else if (bb < 28544) {                // features cvt (25088x512)
    cvt4(features, featf, bb - 16000);
  } else if (bb < 28800) {                // fc1_w cvt
    cvt4(fc1_w, fc1w_h, bb - 28544);
  } else if (bb < 29056) {                // att_wk -> wkfc0[0:512]
    cvt4(att_wk, wkfc0, bb - 28800);
  } else if (bb < 29312) {                // fc0_w -> wkfc0[512:1024]
    cvt4(fc0_w, wkfc0 + (size_t)512 * 512, bb - 29056);
  } else if (bb < 30080) {                // whh -> bcat2[0:1536]
    cvt4(gru_whh, bcat2, bb - 29312);
  } else if (bb < 30336) {                // wq -> bcat2[1536:2048]
    cvt4(att_wq, bcat2 + (size_t)1536 * 512, bb - 30080);
  } else if (bb < 31872) {                // wih split (1536 rows)
    int row = bb - 30336, j = tid * 2;
    float2 a = *(const float2*)(gru_wih + (size_t)row * 1024 + j);
    float2 b = *(const float2*)(gru_wih + (size_t)row * 1024 + 512 + j);
    halfx2 ax; ax[0] = (half_t)a.x; ax[1] = (half_t)a.y;
    halfx2 bx; bx[0] = (half_t)b.x; bx[1] = (half_t)b.y;
    *(halfx2*)(wihx + (size_t)row * 512 + j) = ax;
    *(halfx2*)(wihc + (size_t)row * 512 + j) = bx;
  } else if (bb < 33792) {                // embedding gather (1920 rows)
    int row = bb - 31872;
    int b = row / 15, t = row - b * 15;
    int c = cap[b * 16 + t];
    const float* s = emb + (size_t)c * 512;
    int e = tid * 2;
    float2 v = *(const float2*)(s + e);
    halfx2 o; o[0] = (half_t)v.x; o[1] = (half_t)v.y;
    *(halfx2*)(embg + (size_t)row * 512 + e) = o;
  } else if (bb < 33796) {                // biasc (1024 floats)
    int i = (bb - 33792) * 256 + tid;
    biasc[i] = (i < 512) ? 0.f : fc0_b[i - 512];
  } else {                                // zero ghq+hbuf (321 blocks)
    zbase[(size_t)(bb - 33796) * 256 + tid] = make_float4(0.f, 0.f, 0.f, 0.f);
  }
}

// ---------------- LDS-staged MFMA main loop (m97 structure), f16 A and B -------------
// acc[i][j] += A-tile x B-tile over Kd. smem needs 32768 B.
__device__ __forceinline__ void gemm128_mfma(const half_t* __restrict__ Ap,
                                             const half_t* __restrict__ Bp,
                                             const int Kd,
                                             const int m0, const int n0,
                                             char* smem, floatx4 (&acc)[4][4]) {
  constexpr int ABYTES = 128 * 32 * 2;
  constexpr int BBYTES = 128 * 32 * 2;

  const int l = threadIdx.x & 63;
  const int w = threadIdx.x >> 6;

  const half_t* gA = Ap + (size_t)(m0 + w * 32 + (l >> 2)) * Kd + (l & 3) * 8;
  const half_t* gB = Bp + (size_t)(n0 + w * 32 + (l >> 2)) * Kd + (l & 3) * 8;

  const int fr = l & 15;
  const int kq = (l >> 4) * 8;
  const int mh = (w & 1) * 64;
  const int nh = (w >> 1) * 64;

#pragma unroll
  for (int i = 0; i < 4; ++i)
#pragma unroll
    for (int j = 0; j < 4; ++j) { floatx4 z = {0.f, 0.f, 0.f, 0.f}; acc[i][j] = z; }

  const int NT = Kd >> 5;

  auto stage = [&](int tt) {
    const int k0 = tt * 32;
    char* aD = smem + (tt & 1) * ABYTES;
    char* bD = smem + 2 * ABYTES + (tt & 1) * BBYTES;
    const half_t* g = gA + k0;
    gl16(g, aD + (w * 32) * 64);
    gl16(g + (size_t)16 * Kd, aD + (w * 32 + 16) * 64);
    const half_t* g2 = gB + k0;
    gl16(g2, bD + (w * 32) * 64);
    gl16(g2 + (size_t)16 * Kd, bD + (w * 32 + 16) * 64);
  };

  stage(0);

  for (int t = 0; t < NT; ++t) {
    __syncthreads();                 // drains stage(t)
    if (t + 1 < NT) stage(t + 1);    // prefetch into other buffer
    const char* aB = smem + (t & 1) * ABYTES;
    const char* bB = smem + 2 * ABYTES + (t & 1) * BBYTES;
    halfx8 af[4], bf[4];
#pragma unroll
    for (int i = 0; i < 4; ++i) {
      af[i] = *(const halfx8*)((const half_t*)aB + (size_t)(mh + i * 16 + fr) * 32 + kq);
      bf[i] = *(const halfx8*)((const half_t*)bB + (size_t)(nh + i * 16 + fr) * 32 + kq);
    }
#pragma unroll
    for (int i = 0; i < 4; ++i)
#pragma unroll
      for (int j = 0; j < 4; ++j)
        acc[i][j] = __builtin_amdgcn_mfma_f32_16x16x32_f16(af[i], bf[j], acc[i][j], 0, 0, 0);
  }
}

// standard scattered epilogue
template <bool OUT_F16>
__device__ __forceinline__ void gemm128_body(const half_t* __restrict__ Ap,
                                             const half_t* __restrict__ Bp,
                                             const float* __restrict__ bias,
                                             void* __restrict__ Cp,
                                             const int Kd, const int ldc,
                                             const int m0, const int n0,
                                             char* smem) {
  const int l = threadIdx.x & 63;
  const int w = threadIdx.x >> 6;
  const int mh = (w & 1) * 64;
  const int nh = (w >> 1) * 64;
  floatx4 acc[4][4];
  gemm128_mfma(Ap, Bp, Kd, m0, n0, smem, acc);

#pragma unroll
  for (int j = 0; j < 4; ++j) {
    const int n = n0 + nh + j * 16 + (l & 15);
    const float bv = bias ? bias[n] : 0.0f;
#pragma unroll
    for (int i = 0; i < 4; ++i) {
      const int mb = m0 + mh + i * 16 + (l >> 4) * 4;
#pragma unroll
      for (int r = 0; r < 4; ++r) {
        const float v = acc[i][j][r] + bv;
        const size_t ci = (size_t)(mb + r) * ldc + n;
        if constexpr (OUT_F16) ((half_t*)Cp)[ci] = (half_t)v;
        else                   ((float*)Cp)[ci] = v;
      }
    }
  }
}

// generic wrapper: grid.x = n-tiles (fast), grid.y = m-tiles
template <bool OUT_F16>
__global__ __launch_bounds__(256) void k_gemm_lds(const half_t* __restrict__ Ap,
                                                  const half_t* __restrict__ Bp,
                                                  const float* __restrict__ bias,
                                                  void* __restrict__ Cp,
                                                  int Kd, int ldc) {
  __shared__ __align__(16) char smem[32768];
  gemm128_body<OUT_F16>(Ap, Bp, bias, Cp, Kd, ldc,
                        blockIdx.y * 128, blockIdx.x * 128, smem);
}

// kpfp GEMM: 1568 blocks, XCD-chunked (1568%8==0), works n-fast (8 n-tiles share A panel)
__global__ __launch_bounds__(256) void k_kpfp(const half_t* __restrict__ featf,
                                              const half_t* __restrict__ wkfc0,
                                              const float* __restrict__ biasc,
                                              half_t* __restrict__ kpfp) {
  __shared__ __align__(16) char smem[32768];
  const int w = (blockIdx.x & 7) * 196 + (blockIdx.x >> 3);
  const int n0 = (w & 7) * 128;
  const int m0 = (w >> 3) * 128;
  gemm128_body<true>(featf, wkfc0, biasc, kpfp, 512, 1024, m0, n0, smem);
}

// final fc2 GEMM: C[1920][32000] = hall @ fc2w^T + fc2_b, LDS-coalesced f32 epilogue.
// Epilogue: two half-tile passes; waves with mh==h*64 dump acc into padded [64][132]
// f32 LDS, then all 256 threads write full 512B row segments (float4/lane).
__global__ __launch_bounds__(256) void k_fc2_final(const half_t* __restrict__ hall,
                                                   const half_t* __restrict__ fc2w,
                                                   const float* __restrict__ fc2b,
                                                   float* __restrict__ outp) {
  __shared__ __align__(16) char smem[64 * 132 * 4];   // 33792 B >= 32768 staging
  const int wk = xcd_swz(blockIdx.x, 3750);
  const int m0 = (wk % 15) * 128;
  const int n0 = (wk / 15) * 128;

  const int tid = threadIdx.x;
  const int l = tid & 63;
  const int w = tid >> 6;
  const int nh = (w >> 1) * 64;

  floatx4 acc[4][4];
  gemm128_mfma(hall, fc2w, 512, m0, n0, smem, acc);

  // bias for this thread's output columns (cols n0 + (tid&31)*4 .. +3)
  const float4 bv4 = *(const float4*)(fc2b + n0 + (tid & 31) * 4);
  float* sf = (float*)smem;

#pragma unroll
  for (int h = 0; h < 2; ++h) {
    __syncthreads();                       // smem free (prev pass / mfma reads done)
    if ((w & 1) == h) {
#pragma unroll
      for (int i = 0; i < 4; ++i)
#pragma unroll
        for (int j = 0; j < 4; ++j)
#pragma unroll
          for (int r = 0; r < 4; ++r)
            sf[(i * 16 + (l >> 4) * 4 + r) * 132 + nh + j * 16 + (l & 15)] = acc[i][j][r];
    }
    __syncthreads();
    // 64 rows x 128 cols: 8 rows per iteration (32 lanes/row, float4 each)
#pragma unroll
    for (int it = 0; it < 8; ++it) {
      const int row = it * 8 + (tid >> 5);
      float4 v = *(const float4*)&sf[row * 132 + (tid & 31) * 4];
      v.x += bv4.x; v.y += bv4.y; v.z += bv4.z; v.w += bv4.w;
      *(float4*)(outp + (size_t)(m0 + h * 64 + row) * 32000 + n0 + (tid & 31) * 4) = v;
    }
  }
}

// ---------------- scores: one wave per (b,s): tanh(q_b + kp_bs) . attv ----------------
__global__ __launch_bounds__(256) void k_scores(const half_t* __restrict__ kpfp,
                                                const float* __restrict__ ghq,
                                                const float* __restrict__ attv,
                                                float* __restrict__ scores) {
  int w = blockIdx.x * 4 + (threadIdx.x >> 6);   // 0..25087 == b*196+s
  int l = threadIdx.x & 63;
  int b = w / 196;
  halfx8 kv = *(const halfx8*)(kpfp + (size_t)w * 1024 + l * 8);
  const float* qr = ghq + (size_t)b * 2048 + 1536 + l * 8;
  float4 q0 = *(const float4*)qr;
  float4 q1 = *(const float4*)(qr + 4);
  float4 a0 = *(const float4*)(attv + l * 8);
  float4 a1 = *(const float4*)(attv + l * 8 + 4);
  float acc = a0.x * tanh_f(q0.x + (float)kv[0]);
  acc += a0.y * tanh_f(q0.y + (float)kv[1]);
  acc += a0.z * tanh_f(q0.z + (float)kv[2]);
  acc += a0.w * tanh_f(q0.w + (float)kv[3]);
  acc += a1.x * tanh_f(q1.x + (float)kv[4]);
  acc += a1.y * tanh_f(q1.y + (float)kv[5]);
  acc += a1.z * tanh_f(q1.z + (float)kv[6]);
  acc += a1.w * tanh_f(q1.w + (float)kv[7]);
#pragma unroll
  for (int off = 32; off > 0; off >>= 1) acc += __shfl_xor(acc, off, 64);
  if (l == 0) scores[w] = acc;
}

// ---------------- softmax + ctx = w @ featp (f16 out) ----------------
__global__ __launch_bounds__(256) void k_ctx(const float* __restrict__ scores,
                                             const half_t* __restrict__ kpfp,
                                             half_t* __restrict__ ctxo) {
  const int b = blockIdx.x, kt = blockIdx.y * 128, t = threadIdx.x;
  __shared__ float sw[196], red[256];
  float sc = (t < 196) ? scores[b * 196 + t] : -1e30f;
  red[t] = sc; __syncthreads();
  for (int o = 128; o > 0; o >>= 1) { if (t < o) red[t] = fmaxf(red[t], red[t + o]); __syncthreads(); }
  float mx = red[0]; __syncthreads();
  float e = (t < 196) ? __expf(sc - mx) : 0.f;
  red[t] = e; __syncthreads();
  for (int o = 128; o > 0; o >>= 1) { if (t < o) red[t] += red[t + o]; __syncthreads(); }
  float inv = 1.0f / red[0];
  if (t < 196) sw[t] = e * inv;
  __syncthreads();
  const int kk = t & 127, half = t >> 7, s0 = half * 98;
  const half_t* fp = kpfp + (size_t)(b * 196 + s0) * 1024 + 512 + kt + kk;
  float acc = 0.f;
#pragma unroll 7
  for (int i = 0; i < 98; ++i) acc += sw[s0 + i] * (float)fp[(size_t)i * 1024];
  red[t] = acc; __syncthreads();
  if (t < 128) ctxo[(size_t)b * 512 + kt + t] = (half_t)(red[t] + red[t + 128]);
}

// ---------------- GRU gates, elementwise; writes h_h (contiguous) and hall (b*15+t) ----
__global__ __launch_bounds__(256) void k_gates(const float* __restrict__ gix,
                                               const float* __restrict__ gic,
                                               const float* __restrict__ ghq,
                                               const float* __restrict__ bih,
                                               const float* __restrict__ bhh,
                                               float* __restrict__ hbuf,
                                               half_t* __restrict__ hh,
                                               half_t* __restrict__ hall, int step) {
  int idx = blockIdx.x * 256 + threadIdx.x;  // 0..65535
  int b = idx >> 9, n = idx & 511;
  const float* gx = gix + (size_t)(b * 15 + step) * 1536;
  const float* gc = gic + (size_t)b * 1536;
  const float* gh = ghq + (size_t)b * 2048;
  float ir  = gx[n]        + gc[n]        + bih[n];
  float iz  = gx[n + 512]  + gc[n + 512]  + bih[n + 512];
  float in_ = gx[n + 1024] + gc[n + 1024] + bih[n + 1024];
  float hr  = gh[n]        + bhh[n];
  float hz  = gh[n + 512]  + bhh[n + 512];
  float hn  = gh[n + 1024] + bhh[n + 1024];
  float r = sigmoid_f(ir + hr);
  float z = sigmoid_f(iz + hz);
  float nn = tanh_f(in_ + r * hn);
  float hv = (1.0f - z) * nn + z * hbuf[idx];
  hbuf[idx] = hv;
  half_t h16 = (half_t)hv;
  hh[idx] = h16;
  hall[(size_t)(b * 15 + step) * 512 + n] = h16;
}

extern "C" void kernel_launch(void* const* d_in, const int* in_sizes, int n_in,
                              void* d_out, int out_size, void* d_ws, size_t ws_size,
                              hipStream_t stream) {
  (void)in_sizes; (void)n_in; (void)out_size; (void)ws_size;
  const float* features = (const float*)d_in[0];
  const int*   captions = (const int*)d_in[1];
  const float* emb      = (const float*)d_in[2];
  const float* fc1_w    = (const float*)d_in[3];
  const float* fc1_b    = (const float*)d_in[4];
  const float* att_wq   = (const float*)d_in[5];
  const float* att_wk   = (const float*)d_in[6];
  const float* att_v    = (const float*)d_in[7];
  const float* fc0_w    = (const float*)d_in[8];
  const float* fc0_b    = (const float*)d_in[9];
  const float* gru_wih  = (const float*)d_in[10];
  const float* gru_whh  = (const float*)d_in[11];
  const float* gru_bih  = (const float*)d_in[12];
  const float* gru_bhh  = (const float*)d_in[13];
  const float* fc2_w    = (const float*)d_in[14];
  const float* fc2_b    = (const float*)d_in[15];
  float* out = (float*)d_out;

  // workspace layout (~137 MB)
  char* p = (char*)d_ws;
  half_t* kpfp   = (half_t*)p; p += (size_t)25088 * 1024 * 2; // [:,0:512]=kp, [:,512:1024]=featp+fc0_b
  half_t* fc2w_h = (half_t*)p; p += (size_t)32000 * 512 * 2;
  float*  gix    = (float*)p;  p += (size_t)1920 * 1536 * 4;  // x-path GRU gates, all t
  half_t* wihx_h = (half_t*)p; p += (size_t)1536 * 512 * 2;
  half_t* wihc_h = (half_t*)p; p += (size_t)1536 * 512 * 2;
  half_t* bcat2  = (half_t*)p; p += (size_t)2048 * 512 * 2;   // rows 0:1536=whh, 1536:2048=wq
  half_t* wkfc0  = (half_t*)p; p += (size_t)1024 * 512 * 2;   // rows 0:512=att_wk, 512:1024=fc0_w
  half_t* fc1w_h = (half_t*)p; p += (size_t)512 * 512 * 2;
  half_t* embg_h = (half_t*)p; p += (size_t)1920 * 512 * 2;
  half_t* xproj_h= (half_t*)p; p += (size_t)1920 * 512 * 2;
  float*  biasc  = (float*)p;  p += (size_t)1024 * 4;
  float*  ghq    = (float*)p;  p += (size_t)128 * 2048 * 4;   // cols 0:1536=gh, 1536:2048=q  (zeroed)
  float*  hbuf   = (float*)p;  p += (size_t)128 * 512 * 4;    // zeroed
  int*    bar    = (int*)p;    p += 16;                       // (kept for layout; unused)
  float*  scores = (float*)p;  p += (size_t)128 * 196 * 4;
  float*  gic    = (float*)p;  p += (size_t)128 * 1536 * 4;
  half_t* ctxo   = (half_t*)p; p += (size_t)128 * 512 * 2;
  half_t* h_h    = (half_t*)p; p += (size_t)128 * 512 * 2;
  half_t* featf  = (half_t*)p; p += (size_t)25088 * 512 * 2;  // features, f16
  half_t* hall   = (half_t*)p; p += (size_t)1920 * 512 * 2;   // all h_t, rows b*15+t
  (void)bar;

  // ---- precompute: ONE fused elementwise launch ----
  k_prep<<<dim3(34117), 256, 0, stream>>>(fc2_w, fc2w_h, features, featf,
                                          fc1_w, fc1w_h, att_wk, fc0_w, wkfc0,
                                          gru_whh, att_wq, bcat2,
                                          gru_wih, wihx_h, wihc_h,
                                          emb, captions, embg_h,
                                          fc0_b, biasc, (float4*)ghq);
  // xproj = embg @ fc1_w^T + fc1_b  (1920 x 512, f16 out)
  k_gemm_lds<true><<<dim3(4, 15), 256, 0, stream>>>(embg_h, fc1w_h, fc1_b, xproj_h, 512, 512);
  // kpfp = featf @ [wk|fc0]^T + [0|fc0_b]  (25088 x 1024, f16 out), XCD-chunked
  k_kpfp<<<dim3(1568), 256, 0, stream>>>(featf, wkfc0, biasc, kpfp);
  // gix = xproj @ wihx^T  (1920 x 1536, f32 out)
  k_gemm_lds<false><<<dim3(12, 15), 256, 0, stream>>>(xproj_h, wihx_h, nullptr, gix, 512, 1536);

  // ---- decode loop: 5 launches/step (round-2 structure, verified fastest) ----
  for (int t = 0; t < 15; ++t) {
    k_scores<<<dim3(6272), 256, 0, stream>>>(kpfp, ghq, att_v, scores);
    k_ctx<<<dim3(128, 4), 256, 0, stream>>>(scores, kpfp, ctxo);
    // gic = ctxo @ wihc^T  (128 x 1536)
    k_gemm_lds<false><<<dim3(12, 1), 256, 0, stream>>>(ctxo, wihc_h, nullptr, gic, 512, 1536);
    k_gates<<<dim3(256), 256, 0, stream>>>(gix, gic, ghq, gru_bih, gru_bhh, hbuf, h_h, hall, t);
    // ghq = h @ [whh|wq]^T (for step t+1)  (128 x 2048)
    k_gemm_lds<false><<<dim3(16, 1), 256, 0, stream>>>(h_h, bcat2, nullptr, ghq, 512, 2048);
  }
  // out[b,t,:] = hall[b*15+t] @ fc2^T + fc2_b  (1920 x 32000), one big GEMM
  k_fc2_final<<<dim3(3750), 256, 0, stream>>>(hall, fc2w_h, fc2_b, out);
}